// Round 7
// baseline (415.463 us; speedup 1.0000x reference)
//
#include <hip/hip_runtime.h>

#define B_    64
#define C_    256
#define HW_   1024
#define NPIX  (B_ * HW_)
#define K_    1024
#define TAU_FLAG    2.0e-4f
#define CAND_MARGIN 2.2e-4f
#define MAXFLAG     8192
#define MAXCAND     65536

typedef unsigned short u16;
typedef unsigned int   u32;
typedef unsigned long long u64;
typedef __attribute__((ext_vector_type(8))) __bf16 bf16x8v;
typedef __attribute__((ext_vector_type(4))) float  float4v;
typedef __attribute__((address_space(1))) void gvoid;
typedef __attribute__((address_space(3))) void lvoid;

// Rounding barriers: force a separately-rounded f32 mul/add/sub (defeat
// -ffp-contract=fast fusion and any reassociation across the boundary).
__device__ __forceinline__ float fmul_x(float a, float b) { float p = a * b; asm volatile("" : "+v"(p)); return p; }
__device__ __forceinline__ float fadd_x(float a, float b) { float s = a + b; asm volatile("" : "+v"(s)); return s; }
__device__ __forceinline__ float fsub_x(float a, float b) { float s = a - b; asm volatile("" : "+v"(s)); return s; }

// f32 -> bf16 round-to-nearest-even (finite inputs only), and back.
__device__ __forceinline__ u16 bf16_rne(float f) {
    u32 u = __float_as_uint(f);
    u32 r = u + 0x7FFFu + ((u >> 16) & 1u);
    return (u16)(r >> 16);
}
__device__ __forceinline__ float bf16_to_f(u16 h) { return __uint_as_float(((u32)h) << 16); }

__device__ __forceinline__ uint4 pack8(const u16* h) {
    return make_uint4((u32)h[0] | ((u32)h[1] << 16), (u32)h[2] | ((u32)h[3] << 16),
                      (u32)h[4] | ((u32)h[5] << 16), (u32)h[6] | ((u32)h[7] << 16));
}

// ---------------------------------------------------------------------------
// numpy pairwise sum replica for 256 contiguous squares (unchanged).
// ---------------------------------------------------------------------------
__device__ __forceinline__ float np_sumsq_256(const float* __restrict__ a) {
    float half[2];
#pragma unroll
    for (int h = 0; h < 2; ++h) {
        const float* p = a + h * 128;
        float r[8];
#pragma unroll
        for (int j = 0; j < 8; ++j) r[j] = fmul_x(p[j], p[j]);
        for (int i = 8; i < 128; i += 8)
#pragma unroll
            for (int j = 0; j < 8; ++j) r[j] = fadd_x(r[j], fmul_x(p[i + j], p[i + j]));
        half[h] = fadd_x(fadd_x(fadd_x(r[0], r[1]), fadd_x(r[2], r[3])),
                         fadd_x(fadd_x(r[4], r[5]), fadd_x(r[6], r[7])));
    }
    return fadd_x(half[0], half[1]);
}

// ---------------------------------------------------------------------------
// numpy einsum f32 dot replica (unchanged).
// ---------------------------------------------------------------------------
__device__ float np_einsum_dot_256(const float* __restrict__ xr,
                                   const float* __restrict__ er) {
    float acc0 = 0.f, acc1 = 0.f, acc2 = 0.f, acc3 = 0.f;
    for (int blk = 0; blk < 256; blk += 16) {
#pragma unroll
        for (int sub = 3; sub >= 0; --sub) {
            const int base = blk + sub * 4;
            acc0 = fadd_x(acc0, fmul_x(xr[base + 0], er[base + 0]));
            acc1 = fadd_x(acc1, fmul_x(xr[base + 1], er[base + 1]));
            acc2 = fadd_x(acc2, fmul_x(xr[base + 2], er[base + 2]));
            acc3 = fadd_x(acc3, fmul_x(xr[base + 3], er[base + 3]));
        }
    }
    return fadd_x(fadd_x(acc0, acc2), fadd_x(acc1, acc3));
}

// ---------------------------------------------------------------------------
__global__ __launch_bounds__(256) void zero_kernel(int* pcount, int* ccount) {
    if (threadIdx.x == 0 && blockIdx.x == 0) { *pcount = 0; *ccount = 0; }
}

// e_sq via numpy-pairwise replica (unchanged).
__global__ __launch_bounds__(256) void esq_np_kernel(const float* __restrict__ emb,
                                                     float* __restrict__ esq) {
    const int k = blockIdx.x * 256 + threadIdx.x;
    esq[k] = np_sumsq_256(emb + (size_t)k * C_);
}

// ---------------------------------------------------------------------------
// emb f32 -> hi/lo bf16 planes in STAGED-TILE layout (unchanged):
// chunk (kb*4+ct) is 16KB/plane: [cg8][128][8].
// ---------------------------------------------------------------------------
__global__ __launch_bounds__(256) void cvt_e_kernel(const float* __restrict__ emb,
                                                    u16* __restrict__ et_hi,
                                                    u16* __restrict__ et_lo) {
    const int tid = threadIdx.x;
    const int k  = (blockIdx.x << 5) + (tid & 31);
    const int cg = tid >> 5;
    const int kb = k >> 7;
    const int kr = k & 127;
#pragma unroll
    for (int ct = 0; ct < 4; ++ct) {
        const int c = (ct << 6) + (cg << 3);
        const float* src = emb + (size_t)k * C_ + c;
        u16 h[8], l[8];
#pragma unroll
        for (int i = 0; i < 8; ++i) {
            const float f = src[i];
            h[i] = bf16_rne(f);
            l[i] = bf16_rne(f - bf16_to_f(h[i]));
        }
        const size_t off = ((size_t)((kb << 2) + ct) << 13) + (cg << 10) + (kr << 3);
        *(uint4*)(et_hi + off) = pack8(h);
        *(uint4*)(et_lo + off) = pack8(l);
    }
}

// ---------------------------------------------------------------------------
// x f32 -> hi/lo bf16 planes, NOW 64-ROW CHUNKS for the persistent-x main
// kernel: chunk (pb*4+ct) is 8KB/plane: [cg8][row64][8]. Same RNE values as
// before; only addresses changed.
// ---------------------------------------------------------------------------
__global__ __launch_bounds__(256) void cvt_x_kernel(const float* __restrict__ x,
                                                    u16* __restrict__ xt_hi,
                                                    u16* __restrict__ xt_lo) {
    __shared__ float xs[256][36];       // [c][px(32)+pad]
    const int tid = threadIdx.x;
    const int pix0 = blockIdx.x << 5;   // 32 pixels per block
    const int b   = pix0 >> 10;
    const int hw0 = pix0 & 1023;
#pragma unroll
    for (int r8 = 0; r8 < 8; ++r8) {
        const int u = (r8 << 8) + tid;  // 0..2047 float4s
        const int c = u >> 3;
        const int hq = (u & 7) << 2;
        const float4 v = *(const float4*)(x + ((size_t)b * C_ + c) * HW_ + hw0 + hq);
        *(float4*)&xs[c][hq] = v;
    }
    __syncthreads();
    const int cg = tid >> 5;            // 0..7
    const int px = tid & 31;            // 0..31
    const int pb = pix0 >> 6;           // 64-px chunk index
    const int r  = (pix0 & 63) + px;    // row within chunk
#pragma unroll
    for (int ct = 0; ct < 4; ++ct) {
        const int c = (ct << 6) + (cg << 3);
        u16 h[8], l[8];
#pragma unroll
        for (int i = 0; i < 8; ++i) {
            const float f = xs[c + i][px];
            h[i] = bf16_rne(f);
            l[i] = bf16_rne(f - bf16_to_f(h[i]));
        }
        const size_t off = ((size_t)((pb << 2) + ct) << 12) + (cg << 9) + (r << 3);
        *(uint4*)(xt_hi + off) = pack8(h);
        *(uint4*)(xt_lo + off) = pack8(l);
    }
}

// ---------------------------------------------------------------------------
// MFMA bf16x3 scoring + top-2 + flag, PERSISTENT-X version.
// Block = 64 px x all 1024 codes. x tile (64KB, both planes) staged ONCE into
// LDS; e tiles (32KB per (kt,ct) step) streamed through a double-buffered
// region with prefetch-before-compute. Score arithmetic (loop order kt->ct->
// ks, 3-MFMA accumulation, top-2, tie-break, flag) is bitwise identical to
// the validated round-2 kernel. LDS: 64KB x + 2x32KB e = 128KB; reduction
// arrays alias the e region after the k-loop.
// ---------------------------------------------------------------------------
__global__ __launch_bounds__(256) void vq_main_mfma(const u16* __restrict__ xt_hi,
                                                    const u16* __restrict__ xt_lo,
                                                    const u16* __restrict__ et_hi,
                                                    const u16* __restrict__ et_lo,
                                                    const float* __restrict__ esq,
                                                    int* __restrict__ idx_arr,
                                                    float* __restrict__ m1_arr,
                                                    int* __restrict__ plist,
                                                    int* __restrict__ pcount) {
    __shared__ __align__(16) char smem[131072];
    u16* xls = (u16*)smem;                    // [ct4][pl2][cg8][64][8] u16
    u16* els = (u16*)(smem + 65536);          // [buf2][pl2][cg8][128][8] u16
    float* r_m1 = (float*)(smem + 65536);     // aliases e region (post-loop)
    float* r_m2 = (float*)(smem + 67840);
    int*   r_i1 = (int*)(smem + 70144);

    const int tid  = threadIdx.x;
    const int lane = tid & 63;
    const int wid  = tid >> 6;
    const int wr = wid >> 1, wc = wid & 1;
    const int l15 = lane & 15, l4 = lane >> 4;
    const int p0 = blockIdx.x * 64;

    const char* xhb = (const char*)xt_hi + ((size_t)blockIdx.x << 15); // 32KB/chunk
    const char* xlb = (const char*)xt_lo + ((size_t)blockIdx.x << 15);
    const char* ehb = (const char*)et_hi;
    const char* elb = (const char*)et_lo;

    auto STAGE_E = [&](int step, int buf) {
        const int kt = step >> 2, ct = step & 3;
        const size_t chunk = ((size_t)((kt << 2) + ct)) << 14;   // 16KB/plane
#pragma unroll
        for (int i = 0; i < 8; ++i) {
            const int seg = (i << 2) + wid;      // 0..31 (wave-uniform)
            const int pl = seg >> 4, rem = seg & 15, cg = rem >> 1, h = rem & 1;
            const int ldst = 65536 + (buf << 15) + (pl << 14) + (cg << 11) + (h << 10);
            const char* sb = pl ? elb : ehb;
            __builtin_amdgcn_global_load_lds(
                (gvoid*)(sb + chunk + (cg << 11) + (h << 10) + (lane << 4)),
                (lvoid*)(smem + ldst), 16, 0, 0);
        }
    };

    // prologue: stage x (once) + e step 0 into buf 0
#pragma unroll
    for (int i = 0; i < 16; ++i) {
        const int seg = (i << 2) + wid;          // 0..63 (wave-uniform)
        const int ct = seg >> 4, rem = seg & 15, pl = rem >> 3, cg = rem & 7;
        const int ldst = (ct << 14) + (pl << 13) + (cg << 10);
        const char* sb = pl ? xlb : xhb;
        __builtin_amdgcn_global_load_lds(
            (gvoid*)(sb + (ct << 13) + (cg << 10) + (lane << 4)),
            (lvoid*)(smem + ldst), 16, 0, 0);
    }
    STAGE_E(0, 0);
    __syncthreads();

    float m1[2], m2[2]; int i1[2];
#pragma unroll
    for (int i = 0; i < 2; ++i) { m1[i] = 3.0e38f; m2[i] = 3.0e38f; i1[i] = 0; }

    int step = 0;
    for (int kt = 0; kt < 8; ++kt) {
        const int k0 = kt << 7;
        float4v acc[2][4];
        const float4v zero4 = {0.f, 0.f, 0.f, 0.f};
#pragma unroll
        for (int pf = 0; pf < 2; ++pf)
#pragma unroll
            for (int cf = 0; cf < 4; ++cf) acc[pf][cf] = zero4;

        for (int ct = 0; ct < 4; ++ct, ++step) {
            if (step + 1 < 32) STAGE_E(step + 1, (step + 1) & 1);
            const u16* eb = els + ((step & 1) << 14);   // buf*16384 u16
            const u16* xb = xls + (ct << 13);           // ct*8192 u16
#pragma unroll
            for (int ks = 0; ks < 2; ++ks) {
                const int cgb = (ks << 2) + l4;
                bf16x8v eh[4], el[4];
#pragma unroll
                for (int cf = 0; cf < 4; ++cf) {
                    const int eo = (cgb << 10) + (((wc << 6) + (cf << 4) + l15) << 3);
                    eh[cf] = *(const bf16x8v*)(eb + eo);
                    el[cf] = *(const bf16x8v*)(eb + 8192 + eo);
                }
#pragma unroll
                for (int pf = 0; pf < 2; ++pf) {
                    const int xo = (cgb << 9) + (((wr << 5) + (pf << 4) + l15) << 3);
                    const bf16x8v xh = *(const bf16x8v*)(xb + xo);
                    const bf16x8v xl = *(const bf16x8v*)(xb + 4096 + xo);
#pragma unroll
                    for (int cf = 0; cf < 4; ++cf) {
                        acc[pf][cf] = __builtin_amdgcn_mfma_f32_16x16x32_bf16(eh[cf], xh, acc[pf][cf], 0, 0, 0);
                        acc[pf][cf] = __builtin_amdgcn_mfma_f32_16x16x32_bf16(eh[cf], xl, acc[pf][cf], 0, 0, 0);
                        acc[pf][cf] = __builtin_amdgcn_mfma_f32_16x16x32_bf16(el[cf], xh, acc[pf][cf], 0, 0, 0);
                    }
                }
            }
            __syncthreads();    // drains prefetch (buf^1) + aligns waves
        }
        // top-2 update; k ascending per pixel slot (cf outer, reg inner)
#pragma unroll
        for (int cf = 0; cf < 4; ++cf) {
            const int kb = k0 + (wc << 6) + (cf << 4) + (l4 << 2);
            const float4v ev = *(const float4v*)(esq + kb);
#pragma unroll
            for (int pf = 0; pf < 2; ++pf) {
#pragma unroll
                for (int r = 0; r < 4; ++r) {
                    const float s = fmaf(-2.0f, acc[pf][cf][r], ev[r]);
                    const int k = kb + r;
                    if (s < m1[pf])      { m2[pf] = m1[pf]; m1[pf] = s; i1[pf] = k; }
                    else if (s < m2[pf]) { m2[pf] = s; }
                }
            }
        }
    }

    __syncthreads();    // e buffers dead; reuse as reduction arrays
#pragma unroll
    for (int pf = 0; pf < 2; ++pf) {
        const int p = (wr << 5) + (pf << 4) + l15;
        const int slot = (wc << 2) + l4;
        r_m1[p * 9 + slot] = m1[pf]; r_m2[p * 9 + slot] = m2[pf]; r_i1[p * 9 + slot] = i1[pf];
    }
    __syncthreads();
    if (tid < 64) {
        const int p = tid;
        float M1 = r_m1[p * 9 + 0], M2 = r_m2[p * 9 + 0];
        int   I1 = r_i1[p * 9 + 0];
        for (int t = 1; t < 8; ++t) {
            const float a1 = r_m1[p * 9 + t], a2 = r_m2[p * 9 + t];
            const int   ai = r_i1[p * 9 + t];
            if (a1 < M1 || (a1 == M1 && ai < I1)) { M2 = fminf(M1, a2); M1 = a1; I1 = ai; }
            else                                  { M2 = fminf(M2, a1); }
        }
        const int pix = p0 + p;
        idx_arr[pix] = I1;
        m1_arr[pix] = M1;
        if (M2 - M1 <= TAU_FLAG) {
            int pos = atomicAdd(pcount, 1);
            if (pos < MAXFLAG) plist[pos] = pix;
        }
    }
}

// ---------------------------------------------------------------------------
// gather_x: compact flagged-pixel columns into xg[slot][256]; numpy-pairwise
// sumsq via the 16-chain parallel tree; init best_arr. (unchanged)
// ---------------------------------------------------------------------------
__global__ __launch_bounds__(256) void gather_x_kernel(const float* __restrict__ x,
                                                       const int* __restrict__ plist,
                                                       const int* __restrict__ pcount,
                                                       float* __restrict__ xg,
                                                       float* __restrict__ xsq_arr,
                                                       u64* __restrict__ best_arr) {
    __shared__ float xs[256];
    __shared__ float rsum[16];
    const int nflag = min(*pcount, MAXFLAG);
    const int slot = blockIdx.x;
    if (slot >= nflag) return;
    const int tid = threadIdx.x;
    const int pix = plist[slot];
    const int b = pix >> 10, hw = pix & 1023;
    const float v = x[((size_t)(b * C_ + tid)) * HW_ + hw];
    xs[tid] = v;
    xg[(size_t)slot * C_ + tid] = v;
    __syncthreads();
    if (tid < 16) {
        const int h = tid >> 3, j = tid & 7;
        const float* q = &xs[h * 128];
        float r = fmul_x(q[j], q[j]);
        for (int i = 8; i < 128; i += 8) r = fadd_x(r, fmul_x(q[i + j], q[i + j]));
        rsum[h * 8 + j] = r;
    }
    __syncthreads();
    if (tid == 0) {
        const float h0 = fadd_x(fadd_x(fadd_x(rsum[0], rsum[1]), fadd_x(rsum[2], rsum[3])),
                                fadd_x(fadd_x(rsum[4], rsum[5]), fadd_x(rsum[6], rsum[7])));
        const float h1 = fadd_x(fadd_x(fadd_x(rsum[8], rsum[9]), fadd_x(rsum[10], rsum[11])),
                                fadd_x(fadd_x(rsum[12], rsum[13]), fadd_x(rsum[14], rsum[15])));
        xsq_arr[slot] = fadd_x(h0, h1);
        best_arr[slot] = ~0ull;
    }
}

// ---------------------------------------------------------------------------
// xg f32 (row-major, like emb) -> hi/lo bf16 staged tiles, 128-row chunks
// (scan kernel layout). (unchanged)
// ---------------------------------------------------------------------------
__global__ __launch_bounds__(256) void cvt_xg_kernel(const float* __restrict__ xg,
                                                     const int* __restrict__ pcount,
                                                     u16* __restrict__ xgt_hi,
                                                     u16* __restrict__ xgt_lo) {
    const int nflag = min(*pcount, MAXFLAG);
    if ((int)(blockIdx.x << 5) >= nflag) return;
    const int tid = threadIdx.x;
    const int s  = (blockIdx.x << 5) + (tid & 31);
    const int cg = tid >> 5;
    const int sb = s >> 7;
    const int sr = s & 127;
#pragma unroll
    for (int ct = 0; ct < 4; ++ct) {
        const int c = (ct << 6) + (cg << 3);
        const float* src = xg + (size_t)s * C_ + c;   // tail slots: garbage, guarded later
        u16 h[8], l[8];
#pragma unroll
        for (int i = 0; i < 8; ++i) {
            const float f = src[i];
            h[i] = bf16_rne(f);
            l[i] = bf16_rne(f - bf16_to_f(h[i]));
        }
        const size_t off = ((size_t)((sb << 2) + ct) << 13) + (cg << 10) + (sr << 3);
        *(uint4*)(xgt_hi + off) = pack8(h);
        *(uint4*)(xgt_lo + off) = pack8(l);
    }
}

// ---------------------------------------------------------------------------
// MFMA scan of flagged slots (unchanged from round 6): 128 slots x 128 codes
// per block; candidates appended to a global list.
// ---------------------------------------------------------------------------
__global__ __launch_bounds__(256) void vq_scan_mfma(const u16* __restrict__ xgt_hi,
                                                    const u16* __restrict__ xgt_lo,
                                                    const u16* __restrict__ et_hi,
                                                    const u16* __restrict__ et_lo,
                                                    const float* __restrict__ esq,
                                                    const float* __restrict__ m1_arr,
                                                    const int* __restrict__ plist,
                                                    const int* __restrict__ pcount,
                                                    u32* __restrict__ cand,
                                                    int* __restrict__ ccount) {
    __shared__ __align__(16) u16 xsb_hi[8192], xsb_lo[8192], esb_hi[8192], esb_lo[8192];
    __shared__ float thresh_s[128];

    const int nflag = min(*pcount, MAXFLAG);
    const int st = blockIdx.x >> 3;     // slot tile
    const int kt = blockIdx.x & 7;      // code tile
    const int p0 = st << 7;
    if (p0 >= nflag) return;
    const int tid = threadIdx.x;
    if (tid < 128) {
        const int s = p0 + tid;
        thresh_s[tid] = (s < nflag) ? (m1_arr[plist[s]] + CAND_MARGIN) : -3.0e38f;
    }

    const int lane = tid & 63;
    const int wid  = tid >> 6;
    const int wr = wid >> 1, wc = wid & 1;
    const int l15 = lane & 15, l4 = lane >> 4;

    const char* xhb = (const char*)xgt_hi + ((size_t)st << 16);
    const char* xlb = (const char*)xgt_lo + ((size_t)st << 16);
    const char* ehb = (const char*)et_hi + ((size_t)(kt << 2) << 14);
    const char* elb = (const char*)et_lo + ((size_t)(kt << 2) << 14);

    float4v acc[4][4];
    const float4v zero4 = {0.f, 0.f, 0.f, 0.f};
#pragma unroll
    for (int pf = 0; pf < 4; ++pf)
#pragma unroll
        for (int cf = 0; cf < 4; ++cf) acc[pf][cf] = zero4;

    for (int ct = 0; ct < 4; ++ct) {
        const int coff = ct << 14;
        __syncthreads();
#pragma unroll
        for (int i = 0; i < 4; ++i) {
            const int off = (((i << 2) + wid) << 10);
            const int src = off + (lane << 4);
            __builtin_amdgcn_global_load_lds((gvoid*)(xhb + coff + src),
                (lvoid*)((char*)xsb_hi + off), 16, 0, 0);
            __builtin_amdgcn_global_load_lds((gvoid*)(xlb + coff + src),
                (lvoid*)((char*)xsb_lo + off), 16, 0, 0);
            __builtin_amdgcn_global_load_lds((gvoid*)(ehb + coff + src),
                (lvoid*)((char*)esb_hi + off), 16, 0, 0);
            __builtin_amdgcn_global_load_lds((gvoid*)(elb + coff + src),
                (lvoid*)((char*)esb_lo + off), 16, 0, 0);
        }
        __syncthreads();
#pragma unroll
        for (int ks = 0; ks < 2; ++ks) {
            const int cgb = (ks << 2) + l4;
            const int ebase = (cgb << 7) + (wc << 6) + l15;
            const int xbase = (cgb << 7) + (wr << 6) + l15;
            bf16x8v eh[4], el[4];
#pragma unroll
            for (int cf = 0; cf < 4; ++cf) {
                const int eo = (ebase + (cf << 4)) << 3;
                eh[cf] = *(const bf16x8v*)(esb_hi + eo);
                el[cf] = *(const bf16x8v*)(esb_lo + eo);
            }
#pragma unroll
            for (int pf = 0; pf < 4; ++pf) {
                const int xo = (xbase + (pf << 4)) << 3;
                const bf16x8v xh = *(const bf16x8v*)(xsb_hi + xo);
                const bf16x8v xl = *(const bf16x8v*)(xsb_lo + xo);
#pragma unroll
                for (int cf = 0; cf < 4; ++cf) {
                    acc[pf][cf] = __builtin_amdgcn_mfma_f32_16x16x32_bf16(eh[cf], xh, acc[pf][cf], 0, 0, 0);
                    acc[pf][cf] = __builtin_amdgcn_mfma_f32_16x16x32_bf16(eh[cf], xl, acc[pf][cf], 0, 0, 0);
                    acc[pf][cf] = __builtin_amdgcn_mfma_f32_16x16x32_bf16(el[cf], xh, acc[pf][cf], 0, 0, 0);
                }
            }
        }
    }

    const int k0 = kt << 7;
#pragma unroll
    for (int cf = 0; cf < 4; ++cf) {
        const int kb = k0 + (wc << 6) + (cf << 4) + (l4 << 2);
        const float4v ev = *(const float4v*)(esq + kb);
#pragma unroll
        for (int pf = 0; pf < 4; ++pf) {
            const int slotl = (wr << 6) + (pf << 4) + l15;
            const int slotg = p0 + slotl;
            if (slotg < nflag) {
                const float th = thresh_s[slotl];
#pragma unroll
                for (int r = 0; r < 4; ++r) {
                    const float s = fmaf(-2.0f, acc[pf][cf][r], ev[r]);
                    if (s <= th) {
                        int pos = atomicAdd(ccount, 1);
                        if (pos < MAXCAND) cand[pos] = ((u32)slotg << 10) | (u32)(kb + r);
                    }
                }
            }
        }
    }
}

// ---------------------------------------------------------------------------
// Exact np rescore: one thread per candidate (unchanged).
// ---------------------------------------------------------------------------
__global__ __launch_bounds__(256) void vq_cand_np(const float* __restrict__ xg,
                                                  const float* __restrict__ emb,
                                                  const float* __restrict__ esq,
                                                  const float* __restrict__ xsq_arr,
                                                  const u32* __restrict__ cand,
                                                  const int* __restrict__ ccount,
                                                  u64* __restrict__ best_arr) {
    const int ncand = min(*ccount, MAXCAND);
    const int id = blockIdx.x * 256 + threadIdx.x;
    if (id >= ncand) return;
    const u32 v = cand[id];
    const int slot = (int)(v >> 10);
    const int k = (int)(v & 1023u);
    const float cr = np_einsum_dot_256(xg + (size_t)slot * C_, emb + (size_t)k * C_);
    const float d2 = fadd_x(fsub_x(xsq_arr[slot], fmul_x(2.0f, cr)), esq[k]);
    const u64 pk = ((u64)__float_as_uint(d2) << 32) | (unsigned)k;
    atomicMin(&best_arr[slot], pk);
}

__global__ __launch_bounds__(256) void finalize_kernel(const u64* __restrict__ best_arr,
                                                       const int* __restrict__ plist,
                                                       const int* __restrict__ pcount,
                                                       int* __restrict__ idx_arr) {
    const int nflag = min(*pcount, MAXFLAG);
    const int s = blockIdx.x * 256 + threadIdx.x;
    if (s >= nflag) return;
    idx_arr[plist[s]] = (int)(best_arr[s] & 0xffffffffu);
}

// ---------------------------------------------------------------------------
// gather + STE: out = fl(fl(q - x) + x). Runs LAST. (unchanged)
// ---------------------------------------------------------------------------
__global__ __launch_bounds__(256) void gather_kernel(const float* __restrict__ x,
                                                     const float* __restrict__ emb,
                                                     const int* __restrict__ idx_arr,
                                                     float* __restrict__ out) {
    __shared__ int idx_s[128];
    __shared__ float qs[32][257];
    const int tid = threadIdx.x;
    const int blk = blockIdx.x;
    const int b   = blk >> 3;
    const int hw0 = (blk & 7) << 7;
    if (tid < 128) idx_s[tid] = idx_arr[blk * 128 + tid];
    __syncthreads();
    const int cidx = tid >> 5;          // 0..7
    const int px   = tid & 31;          // 0..31
    for (int ch = 0; ch < 4; ++ch) {
        const int p0c = ch << 5;
#pragma unroll 8
        for (int r = 0; r < 32; ++r)
            qs[r][tid] = emb[(size_t)idx_s[p0c + r] * C_ + tid];
        __syncthreads();
#pragma unroll
        for (int j = 0; j < 32; ++j) {
            const int c = (j << 3) + cidx;
            const size_t o = ((size_t)b * C_ + c) * HW_ + hw0 + p0c + px;
            const float q  = qs[px][c];
            const float xv = x[o];
            out[o] = fadd_x(fsub_x(q, xv), xv);
        }
        __syncthreads();
    }
}

extern "C" void kernel_launch(void* const* d_in, const int* in_sizes, int n_in,
                              void* d_out, int out_size, void* d_ws, size_t ws_size,
                              hipStream_t stream) {
    const float* x   = (const float*)d_in[0];
    const float* emb = (const float*)d_in[1];
    float* out = (float*)d_out;
    char* ws = (char*)d_ws;

    float* esq     = (float*)ws;                 // 4 KB
    int*   pcount  = (int*)(ws + 4096);
    int*   ccount  = (int*)(ws + 8192);
    int*   plist   = (int*)(ws + 12288);         // 32 KB
    float* m1_arr  = (float*)(ws + 65536);       // 256 KB
    int*   idx_arr = (int*)(ws + 327680);        // 256 KB
    float* xsq_arr = (float*)(ws + 589824);      // 32 KB
    u64*   best_arr= (u64*)(ws + 622592);        // 64 KB
    u32*   cand    = (u32*)(ws + 688128);        // 256 KB
    u16*   et_hi   = (u16*)(ws + 983040);        // 512 KB (tiled layout)
    u16*   et_lo   = (u16*)(ws + 1507328);       // 512 KB (total ws ~2 MB)

    // xt hi/lo tiled planes fill the 64 MB output buffer; consumed by vq_main.
    u16* xt_hi = (u16*)d_out;
    u16* xt_lo = (u16*)d_out + 16777216;
    // After vq_main, the out buffer is free until gather: xg + xgt live there.
    float* xg      = (float*)d_out;                           // 8 MB
    u16*   xgt_hi  = (u16*)((char*)d_out + (8u << 20));       // 4 MB
    u16*   xgt_lo  = (u16*)((char*)d_out + (12u << 20));      // 4 MB

    zero_kernel<<<1, 256, 0, stream>>>(pcount, ccount);
    esq_np_kernel<<<K_ / 256, 256, 0, stream>>>(emb, esq);
    cvt_e_kernel<<<K_ / 32, 256, 0, stream>>>(emb, et_hi, et_lo);
    cvt_x_kernel<<<NPIX / 32, 256, 0, stream>>>(x, xt_hi, xt_lo);
    vq_main_mfma<<<NPIX / 64, 256, 0, stream>>>(xt_hi, xt_lo, et_hi, et_lo, esq,
                                                idx_arr, m1_arr, plist, pcount);
    gather_x_kernel<<<MAXFLAG, 256, 0, stream>>>(x, plist, pcount, xg, xsq_arr, best_arr);
    cvt_xg_kernel<<<MAXFLAG / 32, 256, 0, stream>>>(xg, pcount, xgt_hi, xgt_lo);
    vq_scan_mfma<<<(MAXFLAG / 128) * 8, 256, 0, stream>>>(xgt_hi, xgt_lo, et_hi, et_lo,
                                                          esq, m1_arr, plist, pcount,
                                                          cand, ccount);
    vq_cand_np<<<MAXCAND / 256, 256, 0, stream>>>(xg, emb, esq, xsq_arr, cand, ccount,
                                                  best_arr);
    finalize_kernel<<<MAXFLAG / 256, 256, 0, stream>>>(best_arr, plist, pcount, idx_arr);
    gather_kernel<<<NPIX / 128, 256, 0, stream>>>(x, emb, idx_arr, out);
}

// Round 8
// 363.340 us; speedup vs baseline: 1.1435x; 1.1435x over previous
//
#include <hip/hip_runtime.h>

#define B_    64
#define C_    256
#define HW_   1024
#define NPIX  (B_ * HW_)
#define K_    1024
#define TAU_FLAG    2.0e-4f
#define CAND_MARGIN 2.2e-4f
#define MAXFLAG     8192
#define MAXCAND     65536

typedef unsigned short u16;
typedef unsigned int   u32;
typedef unsigned long long u64;
typedef __attribute__((ext_vector_type(8))) __bf16 bf16x8v;
typedef __attribute__((ext_vector_type(4))) float  float4v;
typedef __attribute__((address_space(1))) void gvoid;
typedef __attribute__((address_space(3))) void lvoid;

// Rounding barriers: force a separately-rounded f32 mul/add/sub (defeat
// -ffp-contract=fast fusion and any reassociation across the boundary).
__device__ __forceinline__ float fmul_x(float a, float b) { float p = a * b; asm volatile("" : "+v"(p)); return p; }
__device__ __forceinline__ float fadd_x(float a, float b) { float s = a + b; asm volatile("" : "+v"(s)); return s; }
__device__ __forceinline__ float fsub_x(float a, float b) { float s = a - b; asm volatile("" : "+v"(s)); return s; }

// f32 -> bf16 round-to-nearest-even (finite inputs only), and back.
__device__ __forceinline__ u16 bf16_rne(float f) {
    u32 u = __float_as_uint(f);
    u32 r = u + 0x7FFFu + ((u >> 16) & 1u);
    return (u16)(r >> 16);
}
__device__ __forceinline__ float bf16_to_f(u16 h) { return __uint_as_float(((u32)h) << 16); }

__device__ __forceinline__ uint4 pack8(const u16* h) {
    return make_uint4((u32)h[0] | ((u32)h[1] << 16), (u32)h[2] | ((u32)h[3] << 16),
                      (u32)h[4] | ((u32)h[5] << 16), (u32)h[6] | ((u32)h[7] << 16));
}

// ---------------------------------------------------------------------------
// numpy pairwise sum replica for 256 contiguous squares (unchanged).
// ---------------------------------------------------------------------------
__device__ __forceinline__ float np_sumsq_256(const float* __restrict__ a) {
    float half[2];
#pragma unroll
    for (int h = 0; h < 2; ++h) {
        const float* p = a + h * 128;
        float r[8];
#pragma unroll
        for (int j = 0; j < 8; ++j) r[j] = fmul_x(p[j], p[j]);
        for (int i = 8; i < 128; i += 8)
#pragma unroll
            for (int j = 0; j < 8; ++j) r[j] = fadd_x(r[j], fmul_x(p[i + j], p[i + j]));
        half[h] = fadd_x(fadd_x(fadd_x(r[0], r[1]), fadd_x(r[2], r[3])),
                         fadd_x(fadd_x(r[4], r[5]), fadd_x(r[6], r[7])));
    }
    return fadd_x(half[0], half[1]);
}

// ---------------------------------------------------------------------------
// numpy einsum f32 dot replica (unchanged).
// ---------------------------------------------------------------------------
__device__ float np_einsum_dot_256(const float* __restrict__ xr,
                                   const float* __restrict__ er) {
    float acc0 = 0.f, acc1 = 0.f, acc2 = 0.f, acc3 = 0.f;
    for (int blk = 0; blk < 256; blk += 16) {
#pragma unroll
        for (int sub = 3; sub >= 0; --sub) {
            const int base = blk + sub * 4;
            acc0 = fadd_x(acc0, fmul_x(xr[base + 0], er[base + 0]));
            acc1 = fadd_x(acc1, fmul_x(xr[base + 1], er[base + 1]));
            acc2 = fadd_x(acc2, fmul_x(xr[base + 2], er[base + 2]));
            acc3 = fadd_x(acc3, fmul_x(xr[base + 3], er[base + 3]));
        }
    }
    return fadd_x(fadd_x(acc0, acc2), fadd_x(acc1, acc3));
}

// ---------------------------------------------------------------------------
__global__ __launch_bounds__(256) void zero_kernel(int* pcount, int* ccount) {
    if (threadIdx.x == 0 && blockIdx.x == 0) { *pcount = 0; *ccount = 0; }
}

// e_sq via numpy-pairwise replica (unchanged).
__global__ __launch_bounds__(256) void esq_np_kernel(const float* __restrict__ emb,
                                                     float* __restrict__ esq) {
    const int k = blockIdx.x * 256 + threadIdx.x;
    esq[k] = np_sumsq_256(emb + (size_t)k * C_);
}

// ---------------------------------------------------------------------------
// emb f32 -> hi/lo bf16 planes in STAGED-TILE layout (unchanged):
// chunk (kb*4+ct) is 16KB/plane: [cg8][128][8].
// ---------------------------------------------------------------------------
__global__ __launch_bounds__(256) void cvt_e_kernel(const float* __restrict__ emb,
                                                    u16* __restrict__ et_hi,
                                                    u16* __restrict__ et_lo) {
    const int tid = threadIdx.x;
    const int k  = (blockIdx.x << 5) + (tid & 31);
    const int cg = tid >> 5;
    const int kb = k >> 7;
    const int kr = k & 127;
#pragma unroll
    for (int ct = 0; ct < 4; ++ct) {
        const int c = (ct << 6) + (cg << 3);
        const float* src = emb + (size_t)k * C_ + c;
        u16 h[8], l[8];
#pragma unroll
        for (int i = 0; i < 8; ++i) {
            const float f = src[i];
            h[i] = bf16_rne(f);
            l[i] = bf16_rne(f - bf16_to_f(h[i]));
        }
        const size_t off = ((size_t)((kb << 2) + ct) << 13) + (cg << 10) + (kr << 3);
        *(uint4*)(et_hi + off) = pack8(h);
        *(uint4*)(et_lo + off) = pack8(l);
    }
}

// ---------------------------------------------------------------------------
// x f32 -> hi/lo bf16 planes in 64-ROW chunk layout (unchanged from r7):
// chunk (pb*4+ct) is 8KB/plane: [cg8][row64][8].
// ---------------------------------------------------------------------------
__global__ __launch_bounds__(256) void cvt_x_kernel(const float* __restrict__ x,
                                                    u16* __restrict__ xt_hi,
                                                    u16* __restrict__ xt_lo) {
    __shared__ float xs[256][36];       // [c][px(32)+pad]
    const int tid = threadIdx.x;
    const int pix0 = blockIdx.x << 5;   // 32 pixels per block
    const int b   = pix0 >> 10;
    const int hw0 = pix0 & 1023;
#pragma unroll
    for (int r8 = 0; r8 < 8; ++r8) {
        const int u = (r8 << 8) + tid;  // 0..2047 float4s
        const int c = u >> 3;
        const int hq = (u & 7) << 2;
        const float4 v = *(const float4*)(x + ((size_t)b * C_ + c) * HW_ + hw0 + hq);
        *(float4*)&xs[c][hq] = v;
    }
    __syncthreads();
    const int cg = tid >> 5;            // 0..7
    const int px = tid & 31;            // 0..31
    const int pb = pix0 >> 6;           // 64-px chunk index
    const int r  = (pix0 & 63) + px;    // row within chunk
#pragma unroll
    for (int ct = 0; ct < 4; ++ct) {
        const int c = (ct << 6) + (cg << 3);
        u16 h[8], l[8];
#pragma unroll
        for (int i = 0; i < 8; ++i) {
            const float f = xs[c + i][px];
            h[i] = bf16_rne(f);
            l[i] = bf16_rne(f - bf16_to_f(h[i]));
        }
        const size_t off = ((size_t)((pb << 2) + ct) << 12) + (cg << 9) + (r << 3);
        *(uint4*)(xt_hi + off) = pack8(h);
        *(uint4*)(xt_lo + off) = pack8(l);
    }
}

// ---------------------------------------------------------------------------
// MFMA bf16x3 scoring + top-2 + flag. PERSISTENT-X, HIGH-OCCUPANCY version:
// 512 threads (8 waves, 2x4 wave grid), 64 px x 1024 codes per block.
// LDS 80KB = x_hi 32K + x_lo 32K (persistent, staged once) + single 16KB
// e-buffer (128 codes x 32ch x 2 planes per step). 2 blocks/CU = 16 waves/CU;
// cross-block wave overlap hides the stage drains (m114 mechanism).
// Per-acc MFMA chain iterates kg=0..7 ascending == the validated ct,ks
// channel order -> scores bitwise identical to rounds 2-7. Top-2/merge/flag
// logic identical (merge is order-independent w/ explicit index tie-break).
// ---------------------------------------------------------------------------
__global__ __launch_bounds__(512, 4) void vq_main_mfma(const u16* __restrict__ xt_hi,
                                                       const u16* __restrict__ xt_lo,
                                                       const u16* __restrict__ et_hi,
                                                       const u16* __restrict__ et_lo,
                                                       const float* __restrict__ esq,
                                                       int* __restrict__ idx_arr,
                                                       float* __restrict__ m1_arr,
                                                       int* __restrict__ plist,
                                                       int* __restrict__ pcount) {
    __shared__ __align__(16) char smem[81920];
    // XH [ct4][cg8][row64][8] @0; XL @32768; E @65536 (hi 8KB, lo 8KB)
    float* r_m1 = (float*)(smem + 65536);   // aliases E after the k-loop
    float* r_m2 = (float*)(smem + 69888);
    int*   r_i1 = (int*)(smem + 74240);

    const int tid  = threadIdx.x;
    const int lane = tid & 63;
    const int wid  = tid >> 6;        // 0..7
    const int wr   = wid >> 2;        // 0..1 (pixel half)
    const int wc   = wid & 3;         // 0..3 (code quarter)
    const int l15 = lane & 15, l4 = lane >> 4;
    const int p0 = blockIdx.x * 64;

    const char* xhb = (const char*)xt_hi + ((size_t)blockIdx.x << 15); // 32KB/block
    const char* xlb = (const char*)xt_lo + ((size_t)blockIdx.x << 15);

    // prologue: stage persistent x (hi+lo), linear copy (global layout == LDS)
#pragma unroll
    for (int i = 0; i < 4; ++i) {
        const int seg = (i << 3) + wid;     // 0..31, wave-uniform
        __builtin_amdgcn_global_load_lds((gvoid*)(xhb + (seg << 10) + (lane << 4)),
            (lvoid*)(smem + (seg << 10)), 16, 0, 0);
        __builtin_amdgcn_global_load_lds((gvoid*)(xlb + (seg << 10) + (lane << 4)),
            (lvoid*)(smem + 32768 + (seg << 10)), 16, 0, 0);
    }

    float m1[2], m2[2]; int i1[2];
#pragma unroll
    for (int i = 0; i < 2; ++i) { m1[i] = 3.0e38f; m2[i] = 3.0e38f; i1[i] = 0; }

    for (int kt = 0; kt < 8; ++kt) {
        float4v acc[2][2];
        const float4v zero4 = {0.f, 0.f, 0.f, 0.f};
#pragma unroll
        for (int pf = 0; pf < 2; ++pf)
#pragma unroll
            for (int cf = 0; cf < 2; ++cf) acc[pf][cf] = zero4;

        for (int kg = 0; kg < 8; ++kg) {    // 32-channel steps, ascending
            __syncthreads();                // E free (prev step consumed); x ready @step0
            {   // stage E: 8KB hi + 8KB lo, 2 loads/wave
                const size_t ch = (((size_t)((kt << 2) + (kg >> 1))) << 14) + ((size_t)(kg & 1) << 13);
                __builtin_amdgcn_global_load_lds(
                    (gvoid*)((const char*)et_hi + ch + (wid << 10) + (lane << 4)),
                    (lvoid*)(smem + 65536 + (wid << 10)), 16, 0, 0);
                __builtin_amdgcn_global_load_lds(
                    (gvoid*)((const char*)et_lo + ch + (wid << 10) + (lane << 4)),
                    (lvoid*)(smem + 65536 + 8192 + (wid << 10)), 16, 0, 0);
            }
            __syncthreads();                // E landed (vmcnt drained by all waves)

            bf16x8v eh[2], el[2];
#pragma unroll
            for (int cf = 0; cf < 2; ++cf) {
                const int eo = 65536 + (l4 << 11) + (((wc << 5) + (cf << 4) + l15) << 4);
                eh[cf] = *(const bf16x8v*)(smem + eo);
                el[cf] = *(const bf16x8v*)(smem + 8192 + eo);
            }
            const int ct = kg >> 1;
            const int cg = ((kg & 1) << 2) + l4;
#pragma unroll
            for (int pf = 0; pf < 2; ++pf) {
                const int xo = (ct << 13) + (cg << 10) + (((wr << 5) + (pf << 4) + l15) << 4);
                const bf16x8v xh = *(const bf16x8v*)(smem + xo);
                const bf16x8v xl = *(const bf16x8v*)(smem + 32768 + xo);
#pragma unroll
                for (int cf = 0; cf < 2; ++cf) {
                    acc[pf][cf] = __builtin_amdgcn_mfma_f32_16x16x32_bf16(eh[cf], xh, acc[pf][cf], 0, 0, 0);
                    acc[pf][cf] = __builtin_amdgcn_mfma_f32_16x16x32_bf16(eh[cf], xl, acc[pf][cf], 0, 0, 0);
                    acc[pf][cf] = __builtin_amdgcn_mfma_f32_16x16x32_bf16(el[cf], xh, acc[pf][cf], 0, 0, 0);
                }
            }
        }
        // top-2 update; k ascending per pixel slot (cf outer, reg inner)
        const int k0 = kt << 7;
#pragma unroll
        for (int cf = 0; cf < 2; ++cf) {
            const int kb = k0 + (wc << 5) + (cf << 4) + (l4 << 2);
            const float4v ev = *(const float4v*)(esq + kb);
#pragma unroll
            for (int pf = 0; pf < 2; ++pf) {
#pragma unroll
                for (int r = 0; r < 4; ++r) {
                    const float s = fmaf(-2.0f, acc[pf][cf][r], ev[r]);
                    const int k = kb + r;
                    if (s < m1[pf])      { m2[pf] = m1[pf]; m1[pf] = s; i1[pf] = k; }
                    else if (s < m2[pf]) { m2[pf] = s; }
                }
            }
        }
    }

    __syncthreads();    // all E reads done; alias reduction arrays
#pragma unroll
    for (int pf = 0; pf < 2; ++pf) {
        const int p = (wr << 5) + (pf << 4) + l15;   // 0..63
        const int slot = (wc << 2) + l4;             // 0..15
        r_m1[p * 17 + slot] = m1[pf]; r_m2[p * 17 + slot] = m2[pf]; r_i1[p * 17 + slot] = i1[pf];
    }
    __syncthreads();
    if (tid < 64) {
        const int p = tid;
        float M1 = r_m1[p * 17 + 0], M2 = r_m2[p * 17 + 0];
        int   I1 = r_i1[p * 17 + 0];
        for (int t = 1; t < 16; ++t) {
            const float a1 = r_m1[p * 17 + t], a2 = r_m2[p * 17 + t];
            const int   ai = r_i1[p * 17 + t];
            if (a1 < M1 || (a1 == M1 && ai < I1)) { M2 = fminf(M1, a2); M1 = a1; I1 = ai; }
            else                                  { M2 = fminf(M2, a1); }
        }
        const int pix = p0 + p;
        idx_arr[pix] = I1;
        m1_arr[pix] = M1;
        if (M2 - M1 <= TAU_FLAG) {
            int pos = atomicAdd(pcount, 1);
            if (pos < MAXFLAG) plist[pos] = pix;
        }
    }
}

// ---------------------------------------------------------------------------
// gather_x: compact flagged-pixel columns into xg[slot][256]; numpy-pairwise
// sumsq via the 16-chain parallel tree; init best_arr. (unchanged)
// ---------------------------------------------------------------------------
__global__ __launch_bounds__(256) void gather_x_kernel(const float* __restrict__ x,
                                                       const int* __restrict__ plist,
                                                       const int* __restrict__ pcount,
                                                       float* __restrict__ xg,
                                                       float* __restrict__ xsq_arr,
                                                       u64* __restrict__ best_arr) {
    __shared__ float xs[256];
    __shared__ float rsum[16];
    const int nflag = min(*pcount, MAXFLAG);
    const int slot = blockIdx.x;
    if (slot >= nflag) return;
    const int tid = threadIdx.x;
    const int pix = plist[slot];
    const int b = pix >> 10, hw = pix & 1023;
    const float v = x[((size_t)(b * C_ + tid)) * HW_ + hw];
    xs[tid] = v;
    xg[(size_t)slot * C_ + tid] = v;
    __syncthreads();
    if (tid < 16) {
        const int h = tid >> 3, j = tid & 7;
        const float* q = &xs[h * 128];
        float r = fmul_x(q[j], q[j]);
        for (int i = 8; i < 128; i += 8) r = fadd_x(r, fmul_x(q[i + j], q[i + j]));
        rsum[h * 8 + j] = r;
    }
    __syncthreads();
    if (tid == 0) {
        const float h0 = fadd_x(fadd_x(fadd_x(rsum[0], rsum[1]), fadd_x(rsum[2], rsum[3])),
                                fadd_x(fadd_x(rsum[4], rsum[5]), fadd_x(rsum[6], rsum[7])));
        const float h1 = fadd_x(fadd_x(fadd_x(rsum[8], rsum[9]), fadd_x(rsum[10], rsum[11])),
                                fadd_x(fadd_x(rsum[12], rsum[13]), fadd_x(rsum[14], rsum[15])));
        xsq_arr[slot] = fadd_x(h0, h1);
        best_arr[slot] = ~0ull;
    }
}

// ---------------------------------------------------------------------------
// xg f32 (row-major, like emb) -> hi/lo bf16 staged tiles, 128-row chunks
// (scan kernel layout). (unchanged)
// ---------------------------------------------------------------------------
__global__ __launch_bounds__(256) void cvt_xg_kernel(const float* __restrict__ xg,
                                                     const int* __restrict__ pcount,
                                                     u16* __restrict__ xgt_hi,
                                                     u16* __restrict__ xgt_lo) {
    const int nflag = min(*pcount, MAXFLAG);
    if ((int)(blockIdx.x << 5) >= nflag) return;
    const int tid = threadIdx.x;
    const int s  = (blockIdx.x << 5) + (tid & 31);
    const int cg = tid >> 5;
    const int sb = s >> 7;
    const int sr = s & 127;
#pragma unroll
    for (int ct = 0; ct < 4; ++ct) {
        const int c = (ct << 6) + (cg << 3);
        const float* src = xg + (size_t)s * C_ + c;   // tail slots: garbage, guarded later
        u16 h[8], l[8];
#pragma unroll
        for (int i = 0; i < 8; ++i) {
            const float f = src[i];
            h[i] = bf16_rne(f);
            l[i] = bf16_rne(f - bf16_to_f(h[i]));
        }
        const size_t off = ((size_t)((sb << 2) + ct) << 13) + (cg << 10) + (sr << 3);
        *(uint4*)(xgt_hi + off) = pack8(h);
        *(uint4*)(xgt_lo + off) = pack8(l);
    }
}

// ---------------------------------------------------------------------------
// MFMA scan of flagged slots (unchanged): 128 slots x 128 codes per block;
// candidates appended to a global list.
// ---------------------------------------------------------------------------
__global__ __launch_bounds__(256) void vq_scan_mfma(const u16* __restrict__ xgt_hi,
                                                    const u16* __restrict__ xgt_lo,
                                                    const u16* __restrict__ et_hi,
                                                    const u16* __restrict__ et_lo,
                                                    const float* __restrict__ esq,
                                                    const float* __restrict__ m1_arr,
                                                    const int* __restrict__ plist,
                                                    const int* __restrict__ pcount,
                                                    u32* __restrict__ cand,
                                                    int* __restrict__ ccount) {
    __shared__ __align__(16) u16 xsb_hi[8192], xsb_lo[8192], esb_hi[8192], esb_lo[8192];
    __shared__ float thresh_s[128];

    const int nflag = min(*pcount, MAXFLAG);
    const int st = blockIdx.x >> 3;     // slot tile
    const int kt = blockIdx.x & 7;      // code tile
    const int p0 = st << 7;
    if (p0 >= nflag) return;
    const int tid = threadIdx.x;
    if (tid < 128) {
        const int s = p0 + tid;
        thresh_s[tid] = (s < nflag) ? (m1_arr[plist[s]] + CAND_MARGIN) : -3.0e38f;
    }

    const int lane = tid & 63;
    const int wid  = tid >> 6;
    const int wr = wid >> 1, wc = wid & 1;
    const int l15 = lane & 15, l4 = lane >> 4;

    const char* xhb = (const char*)xgt_hi + ((size_t)st << 16);
    const char* xlb = (const char*)xgt_lo + ((size_t)st << 16);
    const char* ehb = (const char*)et_hi + ((size_t)(kt << 2) << 14);
    const char* elb = (const char*)et_lo + ((size_t)(kt << 2) << 14);

    float4v acc[4][4];
    const float4v zero4 = {0.f, 0.f, 0.f, 0.f};
#pragma unroll
    for (int pf = 0; pf < 4; ++pf)
#pragma unroll
        for (int cf = 0; cf < 4; ++cf) acc[pf][cf] = zero4;

    for (int ct = 0; ct < 4; ++ct) {
        const int coff = ct << 14;
        __syncthreads();
#pragma unroll
        for (int i = 0; i < 4; ++i) {
            const int off = (((i << 2) + wid) << 10);
            const int src = off + (lane << 4);
            __builtin_amdgcn_global_load_lds((gvoid*)(xhb + coff + src),
                (lvoid*)((char*)xsb_hi + off), 16, 0, 0);
            __builtin_amdgcn_global_load_lds((gvoid*)(xlb + coff + src),
                (lvoid*)((char*)xsb_lo + off), 16, 0, 0);
            __builtin_amdgcn_global_load_lds((gvoid*)(ehb + coff + src),
                (lvoid*)((char*)esb_hi + off), 16, 0, 0);
            __builtin_amdgcn_global_load_lds((gvoid*)(elb + coff + src),
                (lvoid*)((char*)esb_lo + off), 16, 0, 0);
        }
        __syncthreads();
#pragma unroll
        for (int ks = 0; ks < 2; ++ks) {
            const int cgb = (ks << 2) + l4;
            const int ebase = (cgb << 7) + (wc << 6) + l15;
            const int xbase = (cgb << 7) + (wr << 6) + l15;
            bf16x8v eh[4], el[4];
#pragma unroll
            for (int cf = 0; cf < 4; ++cf) {
                const int eo = (ebase + (cf << 4)) << 3;
                eh[cf] = *(const bf16x8v*)(esb_hi + eo);
                el[cf] = *(const bf16x8v*)(esb_lo + eo);
            }
#pragma unroll
            for (int pf = 0; pf < 4; ++pf) {
                const int xo = (xbase + (pf << 4)) << 3;
                const bf16x8v xh = *(const bf16x8v*)(xsb_hi + xo);
                const bf16x8v xl = *(const bf16x8v*)(xsb_lo + xo);
#pragma unroll
                for (int cf = 0; cf < 4; ++cf) {
                    acc[pf][cf] = __builtin_amdgcn_mfma_f32_16x16x32_bf16(eh[cf], xh, acc[pf][cf], 0, 0, 0);
                    acc[pf][cf] = __builtin_amdgcn_mfma_f32_16x16x32_bf16(eh[cf], xl, acc[pf][cf], 0, 0, 0);
                    acc[pf][cf] = __builtin_amdgcn_mfma_f32_16x16x32_bf16(el[cf], xh, acc[pf][cf], 0, 0, 0);
                }
            }
        }
    }

    const int k0 = kt << 7;
#pragma unroll
    for (int cf = 0; cf < 4; ++cf) {
        const int kb = k0 + (wc << 6) + (cf << 4) + (l4 << 2);
        const float4v ev = *(const float4v*)(esq + kb);
#pragma unroll
        for (int pf = 0; pf < 4; ++pf) {
            const int slotl = (wr << 6) + (pf << 4) + l15;
            const int slotg = p0 + slotl;
            if (slotg < nflag) {
                const float th = thresh_s[slotl];
#pragma unroll
                for (int r = 0; r < 4; ++r) {
                    const float s = fmaf(-2.0f, acc[pf][cf][r], ev[r]);
                    if (s <= th) {
                        int pos = atomicAdd(ccount, 1);
                        if (pos < MAXCAND) cand[pos] = ((u32)slotg << 10) | (u32)(kb + r);
                    }
                }
            }
        }
    }
}

// ---------------------------------------------------------------------------
// Exact np rescore: one thread per candidate (unchanged).
// ---------------------------------------------------------------------------
__global__ __launch_bounds__(256) void vq_cand_np(const float* __restrict__ xg,
                                                  const float* __restrict__ emb,
                                                  const float* __restrict__ esq,
                                                  const float* __restrict__ xsq_arr,
                                                  const u32* __restrict__ cand,
                                                  const int* __restrict__ ccount,
                                                  u64* __restrict__ best_arr) {
    const int ncand = min(*ccount, MAXCAND);
    const int id = blockIdx.x * 256 + threadIdx.x;
    if (id >= ncand) return;
    const u32 v = cand[id];
    const int slot = (int)(v >> 10);
    const int k = (int)(v & 1023u);
    const float cr = np_einsum_dot_256(xg + (size_t)slot * C_, emb + (size_t)k * C_);
    const float d2 = fadd_x(fsub_x(xsq_arr[slot], fmul_x(2.0f, cr)), esq[k]);
    const u64 pk = ((u64)__float_as_uint(d2) << 32) | (unsigned)k;
    atomicMin(&best_arr[slot], pk);
}

__global__ __launch_bounds__(256) void finalize_kernel(const u64* __restrict__ best_arr,
                                                       const int* __restrict__ plist,
                                                       const int* __restrict__ pcount,
                                                       int* __restrict__ idx_arr) {
    const int nflag = min(*pcount, MAXFLAG);
    const int s = blockIdx.x * 256 + threadIdx.x;
    if (s >= nflag) return;
    idx_arr[plist[s]] = (int)(best_arr[s] & 0xffffffffu);
}

// ---------------------------------------------------------------------------
// gather + STE: out = fl(fl(q - x) + x). Runs LAST. (unchanged)
// ---------------------------------------------------------------------------
__global__ __launch_bounds__(256) void gather_kernel(const float* __restrict__ x,
                                                     const float* __restrict__ emb,
                                                     const int* __restrict__ idx_arr,
                                                     float* __restrict__ out) {
    __shared__ int idx_s[128];
    __shared__ float qs[32][257];
    const int tid = threadIdx.x;
    const int blk = blockIdx.x;
    const int b   = blk >> 3;
    const int hw0 = (blk & 7) << 7;
    if (tid < 128) idx_s[tid] = idx_arr[blk * 128 + tid];
    __syncthreads();
    const int cidx = tid >> 5;          // 0..7
    const int px   = tid & 31;          // 0..31
    for (int ch = 0; ch < 4; ++ch) {
        const int p0c = ch << 5;
#pragma unroll 8
        for (int r = 0; r < 32; ++r)
            qs[r][tid] = emb[(size_t)idx_s[p0c + r] * C_ + tid];
        __syncthreads();
#pragma unroll
        for (int j = 0; j < 32; ++j) {
            const int c = (j << 3) + cidx;
            const size_t o = ((size_t)b * C_ + c) * HW_ + hw0 + p0c + px;
            const float q  = qs[px][c];
            const float xv = x[o];
            out[o] = fadd_x(fsub_x(q, xv), xv);
        }
        __syncthreads();
    }
}

extern "C" void kernel_launch(void* const* d_in, const int* in_sizes, int n_in,
                              void* d_out, int out_size, void* d_ws, size_t ws_size,
                              hipStream_t stream) {
    const float* x   = (const float*)d_in[0];
    const float* emb = (const float*)d_in[1];
    float* out = (float*)d_out;
    char* ws = (char*)d_ws;

    float* esq     = (float*)ws;                 // 4 KB
    int*   pcount  = (int*)(ws + 4096);
    int*   ccount  = (int*)(ws + 8192);
    int*   plist   = (int*)(ws + 12288);         // 32 KB
    float* m1_arr  = (float*)(ws + 65536);       // 256 KB
    int*   idx_arr = (int*)(ws + 327680);        // 256 KB
    float* xsq_arr = (float*)(ws + 589824);      // 32 KB
    u64*   best_arr= (u64*)(ws + 622592);        // 64 KB
    u32*   cand    = (u32*)(ws + 688128);        // 256 KB
    u16*   et_hi   = (u16*)(ws + 983040);        // 512 KB (tiled layout)
    u16*   et_lo   = (u16*)(ws + 1507328);       // 512 KB (total ws ~2 MB)

    // xt hi/lo tiled planes fill the 64 MB output buffer; consumed by vq_main.
    u16* xt_hi = (u16*)d_out;
    u16* xt_lo = (u16*)d_out + 16777216;
    // After vq_main, the out buffer is free until gather: xg + xgt live there.
    float* xg      = (float*)d_out;                           // 8 MB
    u16*   xgt_hi  = (u16*)((char*)d_out + (8u << 20));       // 4 MB
    u16*   xgt_lo  = (u16*)((char*)d_out + (12u << 20));      // 4 MB

    zero_kernel<<<1, 256, 0, stream>>>(pcount, ccount);
    esq_np_kernel<<<K_ / 256, 256, 0, stream>>>(emb, esq);
    cvt_e_kernel<<<K_ / 32, 256, 0, stream>>>(emb, et_hi, et_lo);
    cvt_x_kernel<<<NPIX / 32, 256, 0, stream>>>(x, xt_hi, xt_lo);
    vq_main_mfma<<<NPIX / 64, 512, 0, stream>>>(xt_hi, xt_lo, et_hi, et_lo, esq,
                                                idx_arr, m1_arr, plist, pcount);
    gather_x_kernel<<<MAXFLAG, 256, 0, stream>>>(x, plist, pcount, xg, xsq_arr, best_arr);
    cvt_xg_kernel<<<MAXFLAG / 32, 256, 0, stream>>>(xg, pcount, xgt_hi, xgt_lo);
    vq_scan_mfma<<<(MAXFLAG / 128) * 8, 256, 0, stream>>>(xgt_hi, xgt_lo, et_hi, et_lo,
                                                          esq, m1_arr, plist, pcount,
                                                          cand, ccount);
    vq_cand_np<<<MAXCAND / 256, 256, 0, stream>>>(xg, emb, esq, xsq_arr, cand, ccount,
                                                  best_arr);
    finalize_kernel<<<MAXFLAG / 256, 256, 0, stream>>>(best_arr, plist, pcount, idx_arr);
    gather_kernel<<<NPIX / 128, 256, 0, stream>>>(x, emb, idx_arr, out);
}

// Round 9
// 363.073 us; speedup vs baseline: 1.1443x; 1.0007x over previous
//
#include <hip/hip_runtime.h>

#define B_    64
#define C_    256
#define HW_   1024
#define NPIX  (B_ * HW_)
#define K_    1024
#define TAU_FLAG    2.0e-4f
#define CAND_MARGIN 2.2e-4f
#define MAXFLAG     8192
#define MAXCAND     65536

typedef unsigned short u16;
typedef unsigned int   u32;
typedef unsigned long long u64;
typedef __attribute__((ext_vector_type(8))) __bf16 bf16x8v;
typedef __attribute__((ext_vector_type(4))) float  float4v;
typedef __attribute__((address_space(1))) void gvoid;
typedef __attribute__((address_space(3))) void lvoid;

// Rounding barriers: force a separately-rounded f32 mul/add/sub (defeat
// -ffp-contract=fast fusion and any reassociation across the boundary).
__device__ __forceinline__ float fmul_x(float a, float b) { float p = a * b; asm volatile("" : "+v"(p)); return p; }
__device__ __forceinline__ float fadd_x(float a, float b) { float s = a + b; asm volatile("" : "+v"(s)); return s; }
__device__ __forceinline__ float fsub_x(float a, float b) { float s = a - b; asm volatile("" : "+v"(s)); return s; }

// f32 -> bf16 round-to-nearest-even (finite inputs only), and back.
__device__ __forceinline__ u16 bf16_rne(float f) {
    u32 u = __float_as_uint(f);
    u32 r = u + 0x7FFFu + ((u >> 16) & 1u);
    return (u16)(r >> 16);
}
__device__ __forceinline__ float bf16_to_f(u16 h) { return __uint_as_float(((u32)h) << 16); }

__device__ __forceinline__ uint4 pack8(const u16* h) {
    return make_uint4((u32)h[0] | ((u32)h[1] << 16), (u32)h[2] | ((u32)h[3] << 16),
                      (u32)h[4] | ((u32)h[5] << 16), (u32)h[6] | ((u32)h[7] << 16));
}

// ---------------------------------------------------------------------------
// numpy pairwise sum replica for 256 contiguous squares (unchanged).
// ---------------------------------------------------------------------------
__device__ __forceinline__ float np_sumsq_256(const float* __restrict__ a) {
    float half[2];
#pragma unroll
    for (int h = 0; h < 2; ++h) {
        const float* p = a + h * 128;
        float r[8];
#pragma unroll
        for (int j = 0; j < 8; ++j) r[j] = fmul_x(p[j], p[j]);
        for (int i = 8; i < 128; i += 8)
#pragma unroll
            for (int j = 0; j < 8; ++j) r[j] = fadd_x(r[j], fmul_x(p[i + j], p[i + j]));
        half[h] = fadd_x(fadd_x(fadd_x(r[0], r[1]), fadd_x(r[2], r[3])),
                         fadd_x(fadd_x(r[4], r[5]), fadd_x(r[6], r[7])));
    }
    return fadd_x(half[0], half[1]);
}

// ---------------------------------------------------------------------------
// numpy einsum f32 dot replica (unchanged).
// ---------------------------------------------------------------------------
__device__ float np_einsum_dot_256(const float* __restrict__ xr,
                                   const float* __restrict__ er) {
    float acc0 = 0.f, acc1 = 0.f, acc2 = 0.f, acc3 = 0.f;
    for (int blk = 0; blk < 256; blk += 16) {
#pragma unroll
        for (int sub = 3; sub >= 0; --sub) {
            const int base = blk + sub * 4;
            acc0 = fadd_x(acc0, fmul_x(xr[base + 0], er[base + 0]));
            acc1 = fadd_x(acc1, fmul_x(xr[base + 1], er[base + 1]));
            acc2 = fadd_x(acc2, fmul_x(xr[base + 2], er[base + 2]));
            acc3 = fadd_x(acc3, fmul_x(xr[base + 3], er[base + 3]));
        }
    }
    return fadd_x(fadd_x(acc0, acc2), fadd_x(acc1, acc3));
}

// ---------------------------------------------------------------------------
__global__ __launch_bounds__(256) void zero_kernel(int* pcount, int* ccount) {
    if (threadIdx.x == 0 && blockIdx.x == 0) { *pcount = 0; *ccount = 0; }
}

// e_sq via numpy-pairwise replica (unchanged).
__global__ __launch_bounds__(256) void esq_np_kernel(const float* __restrict__ emb,
                                                     float* __restrict__ esq) {
    const int k = blockIdx.x * 256 + threadIdx.x;
    esq[k] = np_sumsq_256(emb + (size_t)k * C_);
}

// ---------------------------------------------------------------------------
// emb f32 -> hi/lo bf16 planes in STAGED-TILE layout (unchanged):
// chunk (kb*4+ct) is 16KB/plane: [cg8][128][8].
// ---------------------------------------------------------------------------
__global__ __launch_bounds__(256) void cvt_e_kernel(const float* __restrict__ emb,
                                                    u16* __restrict__ et_hi,
                                                    u16* __restrict__ et_lo) {
    const int tid = threadIdx.x;
    const int k  = (blockIdx.x << 5) + (tid & 31);
    const int cg = tid >> 5;
    const int kb = k >> 7;
    const int kr = k & 127;
#pragma unroll
    for (int ct = 0; ct < 4; ++ct) {
        const int c = (ct << 6) + (cg << 3);
        const float* src = emb + (size_t)k * C_ + c;
        u16 h[8], l[8];
#pragma unroll
        for (int i = 0; i < 8; ++i) {
            const float f = src[i];
            h[i] = bf16_rne(f);
            l[i] = bf16_rne(f - bf16_to_f(h[i]));
        }
        const size_t off = ((size_t)((kb << 2) + ct) << 13) + (cg << 10) + (kr << 3);
        *(uint4*)(et_hi + off) = pack8(h);
        *(uint4*)(et_lo + off) = pack8(l);
    }
}

// ---------------------------------------------------------------------------
// x f32 -> hi/lo bf16 planes in 64-ROW chunk layout (unchanged):
// chunk (pb*4+ct) is 8KB/plane: [cg8][row64][8].
// ---------------------------------------------------------------------------
__global__ __launch_bounds__(256) void cvt_x_kernel(const float* __restrict__ x,
                                                    u16* __restrict__ xt_hi,
                                                    u16* __restrict__ xt_lo) {
    __shared__ float xs[256][36];       // [c][px(32)+pad]
    const int tid = threadIdx.x;
    const int pix0 = blockIdx.x << 5;   // 32 pixels per block
    const int b   = pix0 >> 10;
    const int hw0 = pix0 & 1023;
#pragma unroll
    for (int r8 = 0; r8 < 8; ++r8) {
        const int u = (r8 << 8) + tid;  // 0..2047 float4s
        const int c = u >> 3;
        const int hq = (u & 7) << 2;
        const float4 v = *(const float4*)(x + ((size_t)b * C_ + c) * HW_ + hw0 + hq);
        *(float4*)&xs[c][hq] = v;
    }
    __syncthreads();
    const int cg = tid >> 5;            // 0..7
    const int px = tid & 31;            // 0..31
    const int pb = pix0 >> 6;           // 64-px chunk index
    const int r  = (pix0 & 63) + px;    // row within chunk
#pragma unroll
    for (int ct = 0; ct < 4; ++ct) {
        const int c = (ct << 6) + (cg << 3);
        u16 h[8], l[8];
#pragma unroll
        for (int i = 0; i < 8; ++i) {
            const float f = xs[c + i][px];
            h[i] = bf16_rne(f);
            l[i] = bf16_rne(f - bf16_to_f(h[i]));
        }
        const size_t off = ((size_t)((pb << 2) + ct) << 12) + (cg << 9) + (r << 3);
        *(uint4*)(xt_hi + off) = pack8(h);
        *(uint4*)(xt_lo + off) = pack8(l);
    }
}

// ---------------------------------------------------------------------------
// MFMA bf16x3 scoring + top-2 + flag. v3: REGISTER-RESIDENT X + counted-vmcnt
// E pipeline. 512 threads (8 waves, grid 2px-halves x 4 code-quarters),
// 64 px x 1024 codes per block.
//  - X fragments (pf2 x kg8 x hi/lo = 32 b128 = 128 VGPR) loaded once per
//    block by direct per-lane global loads (layout matches LDS image).
//  - LDS = E-only 4-deep ring (4 x 16KB); stage via global_load_lds, 3 steps
//    prefetched ahead; per step: s_waitcnt vmcnt(4) + raw s_barrier (counted
//    vmcnt keeps prefetch in flight across barriers - T3/T4).
//  - Per kg step: 4 ds_read_b128 (E only) + 12 MFMA (was 8 reads).
// Score arithmetic bitwise identical to rounds 2-8: same kg-ascending channel
// order, same 3-MFMA accumulation, same top-2/merge/flag/tie-break.
// kg loop fully unrolled -> all xreg indices static (no scratch).
// ---------------------------------------------------------------------------
__global__ __launch_bounds__(512, 2) void vq_main_mfma(const u16* __restrict__ xt_hi,
                                                       const u16* __restrict__ xt_lo,
                                                       const u16* __restrict__ et_hi,
                                                       const u16* __restrict__ et_lo,
                                                       const float* __restrict__ esq,
                                                       int* __restrict__ idx_arr,
                                                       float* __restrict__ m1_arr,
                                                       int* __restrict__ plist,
                                                       int* __restrict__ pcount) {
    __shared__ __align__(16) char smem[65536];   // E ring: 4 bufs x (8KB hi + 8KB lo)
    float* r_m1 = (float*)smem;                  // aliased after the k-loop
    float* r_m2 = (float*)(smem + 4352);
    int*   r_i1 = (int*)(smem + 8704);

    const int tid  = threadIdx.x;
    const int lane = tid & 63;
    const int wid  = tid >> 6;        // 0..7
    const int wr   = wid >> 2;        // 0..1 (pixel half)
    const int wc   = wid & 3;         // 0..3 (code quarter)
    const int l15 = lane & 15, l4 = lane >> 4;
    const int p0 = blockIdx.x * 64;

    const char* xhb = (const char*)xt_hi + ((size_t)blockIdx.x << 15); // 32KB/block
    const char* xlb = (const char*)xt_lo + ((size_t)blockIdx.x << 15);

    // ---- X fragments -> registers (once per block) ----
    bf16x8v xh_r[2][8], xl_r[2][8];
#pragma unroll
    for (int pf = 0; pf < 2; ++pf) {
#pragma unroll
        for (int kg = 0; kg < 8; ++kg) {
            const int ct = kg >> 1;
            const int cg = ((kg & 1) << 2) + l4;
            const int off = (ct << 13) + (cg << 10) + (((wr << 5) + (pf << 4) + l15) << 4);
            xh_r[pf][kg] = *(const bf16x8v*)(xhb + off);
            xl_r[pf][kg] = *(const bf16x8v*)(xlb + off);
        }
    }

    // ---- prologue: stage E steps 0,1,2 into bufs 0,1,2 ----
#pragma unroll
    for (int s0 = 0; s0 < 3; ++s0) {
        const size_t ch = (((size_t)((s0 >> 1))) << 14) + ((size_t)(s0 & 1) << 13); // kt=0
        const int bb = s0 << 14;
        __builtin_amdgcn_global_load_lds(
            (gvoid*)((const char*)et_hi + ch + (wid << 10) + (lane << 4)),
            (lvoid*)(smem + bb + (wid << 10)), 16, 0, 0);
        __builtin_amdgcn_global_load_lds(
            (gvoid*)((const char*)et_lo + ch + (wid << 10) + (lane << 4)),
            (lvoid*)(smem + bb + 8192 + (wid << 10)), 16, 0, 0);
    }

    float m1[2], m2[2]; int i1[2];
#pragma unroll
    for (int i = 0; i < 2; ++i) { m1[i] = 3.0e38f; m2[i] = 3.0e38f; i1[i] = 0; }

    for (int kt = 0; kt < 8; ++kt) {
        float4v acc[2][2];
        const float4v zero4 = {0.f, 0.f, 0.f, 0.f};
#pragma unroll
        for (int pf = 0; pf < 2; ++pf)
#pragma unroll
            for (int cf = 0; cf < 2; ++cf) acc[pf][cf] = zero4;

#pragma unroll
        for (int kg = 0; kg < 8; ++kg) {
            const int s = (kt << 3) + kg;
            // wait for step s's staging (3 steps = 6 loads may stay in flight)
            asm volatile("s_waitcnt vmcnt(4)" ::: "memory");
            __builtin_amdgcn_s_barrier();
            {   // stage step (s+3)&63 into buf (s+3)&3 (wrap stages are dead writes)
                const int sn = (s + 3) & 63;
                const int ktn = sn >> 3, kgn = sn & 7;
                const size_t ch = (((size_t)((ktn << 2) + (kgn >> 1))) << 14) +
                                  ((size_t)(kgn & 1) << 13);
                const int bb = (sn & 3) << 14;
                __builtin_amdgcn_global_load_lds(
                    (gvoid*)((const char*)et_hi + ch + (wid << 10) + (lane << 4)),
                    (lvoid*)(smem + bb + (wid << 10)), 16, 0, 0);
                __builtin_amdgcn_global_load_lds(
                    (gvoid*)((const char*)et_lo + ch + (wid << 10) + (lane << 4)),
                    (lvoid*)(smem + bb + 8192 + (wid << 10)), 16, 0, 0);
            }
            const char* eb = smem + ((s & 3) << 14);
            bf16x8v eh[2], el[2];
#pragma unroll
            for (int cf = 0; cf < 2; ++cf) {
                const int eo = (l4 << 11) + (((wc << 5) + (cf << 4) + l15) << 4);
                eh[cf] = *(const bf16x8v*)(eb + eo);
                el[cf] = *(const bf16x8v*)(eb + 8192 + eo);
            }
#pragma unroll
            for (int pf = 0; pf < 2; ++pf) {
                const bf16x8v xh = xh_r[pf][kg];
                const bf16x8v xl = xl_r[pf][kg];
#pragma unroll
                for (int cf = 0; cf < 2; ++cf) {
                    acc[pf][cf] = __builtin_amdgcn_mfma_f32_16x16x32_bf16(eh[cf], xh, acc[pf][cf], 0, 0, 0);
                    acc[pf][cf] = __builtin_amdgcn_mfma_f32_16x16x32_bf16(eh[cf], xl, acc[pf][cf], 0, 0, 0);
                    acc[pf][cf] = __builtin_amdgcn_mfma_f32_16x16x32_bf16(el[cf], xh, acc[pf][cf], 0, 0, 0);
                }
            }
        }
        // top-2 update; k ascending per pixel slot (cf outer, reg inner)
        const int k0 = kt << 7;
#pragma unroll
        for (int cf = 0; cf < 2; ++cf) {
            const int kb = k0 + (wc << 5) + (cf << 4) + (l4 << 2);
            const float4v ev = *(const float4v*)(esq + kb);
#pragma unroll
            for (int pf = 0; pf < 2; ++pf) {
#pragma unroll
                for (int r = 0; r < 4; ++r) {
                    const float s = fmaf(-2.0f, acc[pf][cf][r], ev[r]);
                    const int k = kb + r;
                    if (s < m1[pf])      { m2[pf] = m1[pf]; m1[pf] = s; i1[pf] = k; }
                    else if (s < m2[pf]) { m2[pf] = s; }
                }
            }
        }
    }

    // drain remaining prefetch, then reuse LDS for the reduction
    asm volatile("s_waitcnt vmcnt(0)" ::: "memory");
    __builtin_amdgcn_s_barrier();
#pragma unroll
    for (int pf = 0; pf < 2; ++pf) {
        const int p = (wr << 5) + (pf << 4) + l15;   // 0..63
        const int slot = (wc << 2) + l4;             // 0..15
        r_m1[p * 17 + slot] = m1[pf]; r_m2[p * 17 + slot] = m2[pf]; r_i1[p * 17 + slot] = i1[pf];
    }
    __syncthreads();
    if (tid < 64) {
        const int p = tid;
        float M1 = r_m1[p * 17 + 0], M2 = r_m2[p * 17 + 0];
        int   I1 = r_i1[p * 17 + 0];
        for (int t = 1; t < 16; ++t) {
            const float a1 = r_m1[p * 17 + t], a2 = r_m2[p * 17 + t];
            const int   ai = r_i1[p * 17 + t];
            if (a1 < M1 || (a1 == M1 && ai < I1)) { M2 = fminf(M1, a2); M1 = a1; I1 = ai; }
            else                                  { M2 = fminf(M2, a1); }
        }
        const int pix = p0 + p;
        idx_arr[pix] = I1;
        m1_arr[pix] = M1;
        if (M2 - M1 <= TAU_FLAG) {
            int pos = atomicAdd(pcount, 1);
            if (pos < MAXFLAG) plist[pos] = pix;
        }
    }
}

// ---------------------------------------------------------------------------
// gather_x: compact flagged-pixel columns into xg[slot][256]; numpy-pairwise
// sumsq via the 16-chain parallel tree; init best_arr. (unchanged)
// ---------------------------------------------------------------------------
__global__ __launch_bounds__(256) void gather_x_kernel(const float* __restrict__ x,
                                                       const int* __restrict__ plist,
                                                       const int* __restrict__ pcount,
                                                       float* __restrict__ xg,
                                                       float* __restrict__ xsq_arr,
                                                       u64* __restrict__ best_arr) {
    __shared__ float xs[256];
    __shared__ float rsum[16];
    const int nflag = min(*pcount, MAXFLAG);
    const int slot = blockIdx.x;
    if (slot >= nflag) return;
    const int tid = threadIdx.x;
    const int pix = plist[slot];
    const int b = pix >> 10, hw = pix & 1023;
    const float v = x[((size_t)(b * C_ + tid)) * HW_ + hw];
    xs[tid] = v;
    xg[(size_t)slot * C_ + tid] = v;
    __syncthreads();
    if (tid < 16) {
        const int h = tid >> 3, j = tid & 7;
        const float* q = &xs[h * 128];
        float r = fmul_x(q[j], q[j]);
        for (int i = 8; i < 128; i += 8) r = fadd_x(r, fmul_x(q[i + j], q[i + j]));
        rsum[h * 8 + j] = r;
    }
    __syncthreads();
    if (tid == 0) {
        const float h0 = fadd_x(fadd_x(fadd_x(rsum[0], rsum[1]), fadd_x(rsum[2], rsum[3])),
                                fadd_x(fadd_x(rsum[4], rsum[5]), fadd_x(rsum[6], rsum[7])));
        const float h1 = fadd_x(fadd_x(fadd_x(rsum[8], rsum[9]), fadd_x(rsum[10], rsum[11])),
                                fadd_x(fadd_x(rsum[12], rsum[13]), fadd_x(rsum[14], rsum[15])));
        xsq_arr[slot] = fadd_x(h0, h1);
        best_arr[slot] = ~0ull;
    }
}

// ---------------------------------------------------------------------------
// xg f32 (row-major, like emb) -> hi/lo bf16 staged tiles, 128-row chunks
// (scan kernel layout). (unchanged)
// ---------------------------------------------------------------------------
__global__ __launch_bounds__(256) void cvt_xg_kernel(const float* __restrict__ xg,
                                                     const int* __restrict__ pcount,
                                                     u16* __restrict__ xgt_hi,
                                                     u16* __restrict__ xgt_lo) {
    const int nflag = min(*pcount, MAXFLAG);
    if ((int)(blockIdx.x << 5) >= nflag) return;
    const int tid = threadIdx.x;
    const int s  = (blockIdx.x << 5) + (tid & 31);
    const int cg = tid >> 5;
    const int sb = s >> 7;
    const int sr = s & 127;
#pragma unroll
    for (int ct = 0; ct < 4; ++ct) {
        const int c = (ct << 6) + (cg << 3);
        const float* src = xg + (size_t)s * C_ + c;   // tail slots: garbage, guarded later
        u16 h[8], l[8];
#pragma unroll
        for (int i = 0; i < 8; ++i) {
            const float f = src[i];
            h[i] = bf16_rne(f);
            l[i] = bf16_rne(f - bf16_to_f(h[i]));
        }
        const size_t off = ((size_t)((sb << 2) + ct) << 13) + (cg << 10) + (sr << 3);
        *(uint4*)(xgt_hi + off) = pack8(h);
        *(uint4*)(xgt_lo + off) = pack8(l);
    }
}

// ---------------------------------------------------------------------------
// MFMA scan of flagged slots (unchanged): 128 slots x 128 codes per block;
// candidates appended to a global list.
// ---------------------------------------------------------------------------
__global__ __launch_bounds__(256) void vq_scan_mfma(const u16* __restrict__ xgt_hi,
                                                    const u16* __restrict__ xgt_lo,
                                                    const u16* __restrict__ et_hi,
                                                    const u16* __restrict__ et_lo,
                                                    const float* __restrict__ esq,
                                                    const float* __restrict__ m1_arr,
                                                    const int* __restrict__ plist,
                                                    const int* __restrict__ pcount,
                                                    u32* __restrict__ cand,
                                                    int* __restrict__ ccount) {
    __shared__ __align__(16) u16 xsb_hi[8192], xsb_lo[8192], esb_hi[8192], esb_lo[8192];
    __shared__ float thresh_s[128];

    const int nflag = min(*pcount, MAXFLAG);
    const int st = blockIdx.x >> 3;     // slot tile
    const int kt = blockIdx.x & 7;      // code tile
    const int p0 = st << 7;
    if (p0 >= nflag) return;
    const int tid = threadIdx.x;
    if (tid < 128) {
        const int s = p0 + tid;
        thresh_s[tid] = (s < nflag) ? (m1_arr[plist[s]] + CAND_MARGIN) : -3.0e38f;
    }

    const int lane = tid & 63;
    const int wid  = tid >> 6;
    const int wr = wid >> 1, wc = wid & 1;
    const int l15 = lane & 15, l4 = lane >> 4;

    const char* xhb = (const char*)xgt_hi + ((size_t)st << 16);
    const char* xlb = (const char*)xgt_lo + ((size_t)st << 16);
    const char* ehb = (const char*)et_hi + ((size_t)(kt << 2) << 14);
    const char* elb = (const char*)et_lo + ((size_t)(kt << 2) << 14);

    float4v acc[4][4];
    const float4v zero4 = {0.f, 0.f, 0.f, 0.f};
#pragma unroll
    for (int pf = 0; pf < 4; ++pf)
#pragma unroll
        for (int cf = 0; cf < 4; ++cf) acc[pf][cf] = zero4;

    for (int ct = 0; ct < 4; ++ct) {
        const int coff = ct << 14;
        __syncthreads();
#pragma unroll
        for (int i = 0; i < 4; ++i) {
            const int off = (((i << 2) + wid) << 10);
            const int src = off + (lane << 4);
            __builtin_amdgcn_global_load_lds((gvoid*)(xhb + coff + src),
                (lvoid*)((char*)xsb_hi + off), 16, 0, 0);
            __builtin_amdgcn_global_load_lds((gvoid*)(xlb + coff + src),
                (lvoid*)((char*)xsb_lo + off), 16, 0, 0);
            __builtin_amdgcn_global_load_lds((gvoid*)(ehb + coff + src),
                (lvoid*)((char*)esb_hi + off), 16, 0, 0);
            __builtin_amdgcn_global_load_lds((gvoid*)(elb + coff + src),
                (lvoid*)((char*)esb_lo + off), 16, 0, 0);
        }
        __syncthreads();
#pragma unroll
        for (int ks = 0; ks < 2; ++ks) {
            const int cgb = (ks << 2) + l4;
            const int ebase = (cgb << 7) + (wc << 6) + l15;
            const int xbase = (cgb << 7) + (wr << 6) + l15;
            bf16x8v eh[4], el[4];
#pragma unroll
            for (int cf = 0; cf < 4; ++cf) {
                const int eo = (ebase + (cf << 4)) << 3;
                eh[cf] = *(const bf16x8v*)(esb_hi + eo);
                el[cf] = *(const bf16x8v*)(esb_lo + eo);
            }
#pragma unroll
            for (int pf = 0; pf < 4; ++pf) {
                const int xo = (xbase + (pf << 4)) << 3;
                const bf16x8v xh = *(const bf16x8v*)(xsb_hi + xo);
                const bf16x8v xl = *(const bf16x8v*)(xsb_lo + xo);
#pragma unroll
                for (int cf = 0; cf < 4; ++cf) {
                    acc[pf][cf] = __builtin_amdgcn_mfma_f32_16x16x32_bf16(eh[cf], xh, acc[pf][cf], 0, 0, 0);
                    acc[pf][cf] = __builtin_amdgcn_mfma_f32_16x16x32_bf16(eh[cf], xl, acc[pf][cf], 0, 0, 0);
                    acc[pf][cf] = __builtin_amdgcn_mfma_f32_16x16x32_bf16(el[cf], xh, acc[pf][cf], 0, 0, 0);
                }
            }
        }
    }

    const int k0 = kt << 7;
#pragma unroll
    for (int cf = 0; cf < 4; ++cf) {
        const int kb = k0 + (wc << 6) + (cf << 4) + (l4 << 2);
        const float4v ev = *(const float4v*)(esq + kb);
#pragma unroll
        for (int pf = 0; pf < 4; ++pf) {
            const int slotl = (wr << 6) + (pf << 4) + l15;
            const int slotg = p0 + slotl;
            if (slotg < nflag) {
                const float th = thresh_s[slotl];
#pragma unroll
                for (int r = 0; r < 4; ++r) {
                    const float s = fmaf(-2.0f, acc[pf][cf][r], ev[r]);
                    if (s <= th) {
                        int pos = atomicAdd(ccount, 1);
                        if (pos < MAXCAND) cand[pos] = ((u32)slotg << 10) | (u32)(kb + r);
                    }
                }
            }
        }
    }
}

// ---------------------------------------------------------------------------
// Exact np rescore: one thread per candidate (unchanged).
// ---------------------------------------------------------------------------
__global__ __launch_bounds__(256) void vq_cand_np(const float* __restrict__ xg,
                                                  const float* __restrict__ emb,
                                                  const float* __restrict__ esq,
                                                  const float* __restrict__ xsq_arr,
                                                  const u32* __restrict__ cand,
                                                  const int* __restrict__ ccount,
                                                  u64* __restrict__ best_arr) {
    const int ncand = min(*ccount, MAXCAND);
    const int id = blockIdx.x * 256 + threadIdx.x;
    if (id >= ncand) return;
    const u32 v = cand[id];
    const int slot = (int)(v >> 10);
    const int k = (int)(v & 1023u);
    const float cr = np_einsum_dot_256(xg + (size_t)slot * C_, emb + (size_t)k * C_);
    const float d2 = fadd_x(fsub_x(xsq_arr[slot], fmul_x(2.0f, cr)), esq[k]);
    const u64 pk = ((u64)__float_as_uint(d2) << 32) | (unsigned)k;
    atomicMin(&best_arr[slot], pk);
}

__global__ __launch_bounds__(256) void finalize_kernel(const u64* __restrict__ best_arr,
                                                       const int* __restrict__ plist,
                                                       const int* __restrict__ pcount,
                                                       int* __restrict__ idx_arr) {
    const int nflag = min(*pcount, MAXFLAG);
    const int s = blockIdx.x * 256 + threadIdx.x;
    if (s >= nflag) return;
    idx_arr[plist[s]] = (int)(best_arr[s] & 0xffffffffu);
}

// ---------------------------------------------------------------------------
// gather + STE: out = fl(fl(q - x) + x). Runs LAST. (unchanged)
// ---------------------------------------------------------------------------
__global__ __launch_bounds__(256) void gather_kernel(const float* __restrict__ x,
                                                     const float* __restrict__ emb,
                                                     const int* __restrict__ idx_arr,
                                                     float* __restrict__ out) {
    __shared__ int idx_s[128];
    __shared__ float qs[32][257];
    const int tid = threadIdx.x;
    const int blk = blockIdx.x;
    const int b   = blk >> 3;
    const int hw0 = (blk & 7) << 7;
    if (tid < 128) idx_s[tid] = idx_arr[blk * 128 + tid];
    __syncthreads();
    const int cidx = tid >> 5;          // 0..7
    const int px   = tid & 31;          // 0..31
    for (int ch = 0; ch < 4; ++ch) {
        const int p0c = ch << 5;
#pragma unroll 8
        for (int r = 0; r < 32; ++r)
            qs[r][tid] = emb[(size_t)idx_s[p0c + r] * C_ + tid];
        __syncthreads();
#pragma unroll
        for (int j = 0; j < 32; ++j) {
            const int c = (j << 3) + cidx;
            const size_t o = ((size_t)b * C_ + c) * HW_ + hw0 + p0c + px;
            const float q  = qs[px][c];
            const float xv = x[o];
            out[o] = fadd_x(fsub_x(q, xv), xv);
        }
        __syncthreads();
    }
}

extern "C" void kernel_launch(void* const* d_in, const int* in_sizes, int n_in,
                              void* d_out, int out_size, void* d_ws, size_t ws_size,
                              hipStream_t stream) {
    const float* x   = (const float*)d_in[0];
    const float* emb = (const float*)d_in[1];
    float* out = (float*)d_out;
    char* ws = (char*)d_ws;

    float* esq     = (float*)ws;                 // 4 KB
    int*   pcount  = (int*)(ws + 4096);
    int*   ccount  = (int*)(ws + 8192);
    int*   plist   = (int*)(ws + 12288);         // 32 KB
    float* m1_arr  = (float*)(ws + 65536);       // 256 KB
    int*   idx_arr = (int*)(ws + 327680);        // 256 KB
    float* xsq_arr = (float*)(ws + 589824);      // 32 KB
    u64*   best_arr= (u64*)(ws + 622592);        // 64 KB
    u32*   cand    = (u32*)(ws + 688128);        // 256 KB
    u16*   et_hi   = (u16*)(ws + 983040);        // 512 KB (tiled layout)
    u16*   et_lo   = (u16*)(ws + 1507328);       // 512 KB (total ws ~2 MB)

    // xt hi/lo tiled planes fill the 64 MB output buffer; consumed by vq_main.
    u16* xt_hi = (u16*)d_out;
    u16* xt_lo = (u16*)d_out + 16777216;
    // After vq_main, the out buffer is free until gather: xg + xgt live there.
    float* xg      = (float*)d_out;                           // 8 MB
    u16*   xgt_hi  = (u16*)((char*)d_out + (8u << 20));       // 4 MB
    u16*   xgt_lo  = (u16*)((char*)d_out + (12u << 20));      // 4 MB

    zero_kernel<<<1, 256, 0, stream>>>(pcount, ccount);
    esq_np_kernel<<<K_ / 256, 256, 0, stream>>>(emb, esq);
    cvt_e_kernel<<<K_ / 32, 256, 0, stream>>>(emb, et_hi, et_lo);
    cvt_x_kernel<<<NPIX / 32, 256, 0, stream>>>(x, xt_hi, xt_lo);
    vq_main_mfma<<<NPIX / 64, 512, 0, stream>>>(xt_hi, xt_lo, et_hi, et_lo, esq,
                                                idx_arr, m1_arr, plist, pcount);
    gather_x_kernel<<<MAXFLAG, 256, 0, stream>>>(x, plist, pcount, xg, xsq_arr, best_arr);
    cvt_xg_kernel<<<MAXFLAG / 32, 256, 0, stream>>>(xg, pcount, xgt_hi, xgt_lo);
    vq_scan_mfma<<<(MAXFLAG / 128) * 8, 256, 0, stream>>>(xgt_hi, xgt_lo, et_hi, et_lo,
                                                          esq, m1_arr, plist, pcount,
                                                          cand, ccount);
    vq_cand_np<<<MAXCAND / 256, 256, 0, stream>>>(xg, emb, esq, xsq_arr, cand, ccount,
                                                  best_arr);
    finalize_kernel<<<MAXFLAG / 256, 256, 0, stream>>>(best_arr, plist, pcount, idx_arr);
    gather_kernel<<<NPIX / 128, 256, 0, stream>>>(x, emb, idx_arr, out);
}